// Round 7
// baseline (134.503 us; speedup 1.0000x reference)
//
#include <hip/hip_runtime.h>
#include <hip/hip_bf16.h>
#include <math.h>

typedef __hip_bfloat16 bf16;
typedef __attribute__((ext_vector_type(8))) short short8;
typedef __attribute__((ext_vector_type(4))) float floatx4;

static constexpr int Bn = 2, Sn = 2048, Hn = 16, DHn = 64, DIMn = 1024;
static constexpr int Mn = Bn * Sn;  // 4096 tokens

#if __has_builtin(__builtin_amdgcn_exp2f)
#define EXP2(x) __builtin_amdgcn_exp2f(x)
#else
#define EXP2(x) exp2f(x)
#endif

__device__ __forceinline__ unsigned short bfbits(float f) {
  union { __hip_bfloat16 h; unsigned short u; } cv;
  cv.h = __float2bfloat16(f);
  return cv.u;
}

__device__ __forceinline__ float bf2f(unsigned short u) {
  union { float f; unsigned int u; } cv;
  cv.u = ((unsigned int)u) << 16;
  return cv.f;
}

// async global->LDS, 16B per lane. dst is wave-uniform base; HW adds lane*16.
__device__ __forceinline__ void gload_lds16(const void* g, void* l) {
  __builtin_amdgcn_global_load_lds(
      (const __attribute__((address_space(1))) uint32_t*)g,
      (__attribute__((address_space(3))) uint32_t*)l, 16, 0, 0);
}

// counted waits (T4). sched_barrier pins per rule #18.
template <int N>
__device__ __forceinline__ void wait_vm() {
  if constexpr (N == 0) asm volatile("s_waitcnt vmcnt(0)" ::: "memory");
  else if constexpr (N == 2) asm volatile("s_waitcnt vmcnt(2)" ::: "memory");
  else if constexpr (N == 3) asm volatile("s_waitcnt vmcnt(3)" ::: "memory");
  else asm volatile("s_waitcnt vmcnt(4)" ::: "memory");
  __builtin_amdgcn_sched_barrier(0);
}

// ---------------- f32 -> bf16 convert (vectorized, 4/thread) ----------------
__global__ void cvt_kernel(const float* __restrict__ src, unsigned short* __restrict__ dst, int n4) {
  int i = blockIdx.x * blockDim.x + threadIdx.x;
  if (i >= n4) return;
  float4 v = ((const float4*)src)[i];
  ushort4 o;
  o.x = bfbits(v.x); o.y = bfbits(v.y); o.z = bfbits(v.z); o.w = bfbits(v.w);
  ((ushort4*)dst)[i] = o;
}

// 4 weight matrices (1M elems each) in one launch: grid (1024, 4)
__global__ void cvt4_kernel(const float* __restrict__ a0, const float* __restrict__ a1,
                            const float* __restrict__ a2, const float* __restrict__ a3,
                            unsigned short* __restrict__ o0, unsigned short* __restrict__ o1,
                            unsigned short* __restrict__ o2, unsigned short* __restrict__ o3) {
  const float* s = (blockIdx.y == 0) ? a0 : (blockIdx.y == 1) ? a1 : (blockIdx.y == 2) ? a2 : a3;
  unsigned short* d = (blockIdx.y == 0) ? o0 : (blockIdx.y == 1) ? o1 : (blockIdx.y == 2) ? o2 : o3;
  int i = blockIdx.x * 256 + threadIdx.x;
  float4 v = ((const float4*)s)[i];
  ushort4 o;
  o.x = bfbits(v.x); o.y = bfbits(v.y); o.z = bfbits(v.z); o.w = bfbits(v.w);
  ((ushort4*)d)[i] = o;
}

// ---------------- RoPE cos/sin tables: [S][32] ----------------
__global__ void rope_tab_kernel(float* __restrict__ tc, float* __restrict__ ts) {
  int t = blockIdx.x * 256 + threadIdx.x;  // 2048*32 = 65536
  int pos = t >> 5, i = t & 31;
  float f = powf(10000.0f, -(float)i * (1.0f / 32.0f));
  float a = (float)pos * f;
  tc[t] = cosf(a);
  ts[t] = sinf(a);
}

// ---------------- fused QKV GEMM, 128x64 tiles ----------------
// grid (32, 48): sel = blockIdx.y>>4, n0 = (blockIdx.y&15)*64.
// Per wave 64x32 out (8 MFMA/iter). 24KB LDS -> ~6 blocks/CU.
__global__ __launch_bounds__(256, 6) void qkv_kernel(
    const bf16* __restrict__ A,
    const bf16* __restrict__ Wq, const bf16* __restrict__ Wk, const bf16* __restrict__ Wv,
    const float* __restrict__ bq, const float* __restrict__ bk, const float* __restrict__ bv,
    unsigned short* __restrict__ qo, unsigned short* __restrict__ ko,
    unsigned short* __restrict__ vt) {
  __shared__ bf16 smem[12288];  // sA[2][4096] | sB[2][2048]; V^T reuses as ct
  bf16* sAp = smem;
  bf16* sBp = smem + 8192;
  const int sel = blockIdx.y >> 4;
  const bf16* Bw = (sel == 0) ? Wq : (sel == 1) ? Wk : Wv;
  const float* bias = (sel == 0) ? bq : (sel == 1) ? bk : bv;
  const int tid = threadIdx.x;
  const int lane = tid & 63, wave = tid >> 6;
  const int fr = lane & 15, fq = lane >> 4;
  const int wm0 = (wave >> 1) * 64, wn0 = (wave & 1) * 32;
  const int m0 = blockIdx.x * 128, n0 = (blockIdx.y & 15) * 64;

  floatx4 acc[4][2] = {};
  const int sr = tid >> 2;
  const int sc8 = (tid & 3) * 8;

  auto stage = [&](int buf, int k0) {
    gload_lds16(A + (size_t)(m0 + sr) * 1024 + k0 + sc8, sAp + buf * 4096 + wave * 512);
    gload_lds16(A + (size_t)(m0 + 64 + sr) * 1024 + k0 + sc8,
                sAp + buf * 4096 + 2048 + wave * 512);
    gload_lds16(Bw + (size_t)(n0 + sr) * 1024 + k0 + sc8, sBp + buf * 2048 + wave * 512);
  };

  stage(0, 0);
  stage(1, 32);
  int cur = 0;
  for (int k0 = 0; k0 < 1024; k0 += 32) {
    if (k0 + 32 < 1024) wait_vm<3>(); else wait_vm<0>();
    __builtin_amdgcn_s_barrier();
    __builtin_amdgcn_sched_barrier(0);
    short8 af[4], bfr[2];
#pragma unroll
    for (int mi = 0; mi < 4; ++mi)
      af[mi] = *(const short8*)(sAp + cur * 4096 + (wm0 + mi * 16 + fr) * 32 + fq * 8);
#pragma unroll
    for (int ni = 0; ni < 2; ++ni)
      bfr[ni] = *(const short8*)(sBp + cur * 2048 + (wn0 + ni * 16 + fr) * 32 + fq * 8);
#pragma unroll
    for (int mi = 0; mi < 4; ++mi)
#pragma unroll
      for (int ni = 0; ni < 2; ++ni)
        acc[mi][ni] = __builtin_amdgcn_mfma_f32_16x16x32_bf16(af[mi], bfr[ni], acc[mi][ni], 0, 0, 0);
    __builtin_amdgcn_sched_barrier(0);
    __builtin_amdgcn_s_barrier();
    if (k0 + 64 < 1024) stage(cur, k0 + 64);
    cur ^= 1;
  }

  if (sel < 2) {
    unsigned short* dst = (sel == 0) ? qo : ko;
#pragma unroll
    for (int mi = 0; mi < 4; ++mi)
#pragma unroll
      for (int ni = 0; ni < 2; ++ni) {
        int n = n0 + wn0 + ni * 16 + fr;
        float bi = bias[n];
#pragma unroll
        for (int j = 0; j < 4; ++j) {
          int m = m0 + wm0 + mi * 16 + fq * 4 + j;
          dst[(size_t)m * 1024 + n] = bfbits(acc[mi][ni][j] + bi);
        }
      }
  } else {
    // V: transpose tile through LDS (XOR-swizzled), write coalesced 16B runs.
    __syncthreads();
    char* ct = (char*)smem;  // [nl 64][ml 128] bf16, row 256B, byte ^= (nl&15)<<4
#pragma unroll
    for (int mi = 0; mi < 4; ++mi)
#pragma unroll
      for (int ni = 0; ni < 2; ++ni) {
        int nl = wn0 + ni * 16 + fr;
        float bi = bias[n0 + nl];
#pragma unroll
        for (int j = 0; j < 4; j += 2) {
          int ml = wm0 + mi * 16 + fq * 4 + j;
          unsigned int u = (unsigned int)bfbits(acc[mi][ni][j] + bi) |
                           ((unsigned int)bfbits(acc[mi][ni][j + 1] + bi) << 16);
          *(unsigned int*)(ct + nl * 256 + ((ml * 2) ^ ((nl & 15) << 4))) = u;
        }
      }
    __syncthreads();
    int nl2 = tid >> 2, ch = tid & 3;
    int ng = n0 + nl2;
    int hh = ng >> 6, dd = ng & 63;
    int b = m0 >> 11, s0 = m0 & 2047;
    unsigned short* orow = vt + (((size_t)b * 16 + hh) * 64 + dd) * 2048 + s0;
#pragma unroll
    for (int c = 0; c < 4; ++c) {
      int mb = ch * 32 + c * 8;
      short8 v8 = *(const short8*)(ct + nl2 * 256 + ((mb * 2) ^ ((nl2 & 15) << 4)));
      *(short8*)(orow + mb) = v8;
    }
  }
}

// ---------------- Wo GEMM: 64x64 tiles, f32 out ----------------
// grid (64, 16) = 1024 blocks -> 4/CU (vs 1/CU at 128^2).
__global__ __launch_bounds__(256, 4) void gemm_bt_kernel(
    const bf16* __restrict__ A, const bf16* __restrict__ Bw,
    const float* __restrict__ bias, float* __restrict__ Cf) {
  __shared__ bf16 smem[8192];  // sA[2][2048] | sB[2][2048]
  bf16* sAp = smem;
  bf16* sBp = smem + 4096;
  const int tid = threadIdx.x;
  const int lane = tid & 63, wave = tid >> 6;
  const int fr = lane & 15, fq = lane >> 4;
  const int wm0 = (wave >> 1) * 32, wn0 = (wave & 1) * 32;
  const int m0 = blockIdx.x * 64, n0 = blockIdx.y * 64;

  floatx4 acc[2][2] = {};
  const int sr = tid >> 2;
  const int sc8 = (tid & 3) * 8;

  auto stage = [&](int buf, int k0) {
    gload_lds16(A + (size_t)(m0 + sr) * 1024 + k0 + sc8, sAp + buf * 2048 + wave * 512);
    gload_lds16(Bw + (size_t)(n0 + sr) * 1024 + k0 + sc8, sBp + buf * 2048 + wave * 512);
  };

  stage(0, 0);
  stage(1, 32);
  int cur = 0;
  for (int k0 = 0; k0 < 1024; k0 += 32) {
    if (k0 + 32 < 1024) wait_vm<2>(); else wait_vm<0>();
    __builtin_amdgcn_s_barrier();
    __builtin_amdgcn_sched_barrier(0);
    short8 af[2], bfr[2];
#pragma unroll
    for (int mi = 0; mi < 2; ++mi)
      af[mi] = *(const short8*)(sAp + cur * 2048 + (wm0 + mi * 16 + fr) * 32 + fq * 8);
#pragma unroll
    for (int ni = 0; ni < 2; ++ni)
      bfr[ni] = *(const short8*)(sBp + cur * 2048 + (wn0 + ni * 16 + fr) * 32 + fq * 8);
#pragma unroll
    for (int mi = 0; mi < 2; ++mi)
#pragma unroll
      for (int ni = 0; ni < 2; ++ni)
        acc[mi][ni] = __builtin_amdgcn_mfma_f32_16x16x32_bf16(af[mi], bfr[ni], acc[mi][ni], 0, 0, 0);
    __builtin_amdgcn_sched_barrier(0);
    __builtin_amdgcn_s_barrier();
    if (k0 + 64 < 1024) stage(cur, k0 + 64);
    cur ^= 1;
  }

#pragma unroll
  for (int mi = 0; mi < 2; ++mi)
#pragma unroll
    for (int ni = 0; ni < 2; ++ni) {
      int n = n0 + wn0 + ni * 16 + fr;
      float bi = bias[n];
#pragma unroll
      for (int j = 0; j < 4; ++j) {
        int m = m0 + wm0 + mi * 16 + fq * 4 + j;
        Cf[(size_t)m * 1024 + n] = acc[mi][ni][j] + bi;
      }
    }
}

// ---------------- RoPE + l2norm: bf16 [B,S,H,64] -> bf16 [B,H,S,64] ----------------
__global__ __launch_bounds__(256) void rope_norm_kernel(
    const unsigned short* __restrict__ qf, const unsigned short* __restrict__ kf,
    const float* __restrict__ tc, const float* __restrict__ ts,
    unsigned short* __restrict__ qb, unsigned short* __restrict__ kb) {
  int gr = blockIdx.x * 8 + (threadIdx.x >> 5);  // row id over 2*65536
  int j = threadIdx.x & 31;                      // pair index within head dim
  const unsigned short* src;
  unsigned short* dst;
  int rr;
  if (gr < Mn * Hn) { src = qf; dst = qb; rr = gr; }
  else { src = kf; dst = kb; rr = gr - Mn * Hn; }
  int h = rr & 15, bs = rr >> 4;
  int s = bs & 2047, b = bs >> 11;
  ushort2 xr = *(const ushort2*)(src + (size_t)bs * 1024 + h * 64 + 2 * j);
  float x0 = bf2f(xr.x), x1 = bf2f(xr.y);
  float c = tc[s * 32 + j], sn = ts[s * 32 + j];
  float y0 = x0 * c - x1 * sn;
  float y1 = x1 * c + x0 * sn;
  float ssq = y0 * y0 + y1 * y1;
#pragma unroll
  for (int msk = 1; msk < 32; msk <<= 1) ssq += __shfl_xor(ssq, msk);
  float inv = rsqrtf(ssq + 1e-6f);
  size_t o = (((size_t)b * 16 + h) * 2048 + s) * 64 + 2 * j;
  ushort2 pk;
  pk.x = bfbits(y0 * inv);
  pk.y = bfbits(y1 * inv);
  *(ushort2*)(dst + o) = pk;
}

// ---------------- causal flash attention, split-letter paired q-tiles ----------------
// grid 1024 (1D). Balanced dispatch permutation: co-resident blocks (ids
// differing by 256) get xq values {j, 31-j} so per-CU iteration sums are
// constant. Waves 0,1 own q-tile xq; waves 2,3 own 63-xq. KVBLK=64 dbuf,
// counted vmcnt. LDS 40KB -> 4 blocks/CU.
__global__ __launch_bounds__(256, 4) void attn_kernel(
    const bf16* __restrict__ qb, const bf16* __restrict__ kb, const bf16* __restrict__ vt,
    const float* __restrict__ ls, unsigned short* __restrict__ out) {
  __shared__ bf16 sK[2][64 * 64];   // [kv][d], 128B rows, swz (row&7)<<4
  __shared__ bf16 sV[2][64 * 64];   // [d][kv], 128B rows, swz (row&7)<<4
  __shared__ char p_lds[4][2048];   // per wave: 16x64 bf16, swz (prow&7)<<4
  const int bid = blockIdx.x;
  const int rr4 = bid >> 8, g = bid & 255, jj = g & 31;
  const int xq = (rr4 & 1) ? (31 - jj) : jj;
  const int bh = (g >> 5) + 8 * rr4;
  const int q0A = xq * 32, q0B = (63 - xq) * 32;
  const int tid = threadIdx.x;
  const int lane = tid & 63, wave = tid >> 6;
  const int fr = lane & 15, fq = lane >> 4;
  const int myq0 = (wave >= 2) ? q0B : q0A;
  const int base = myq0 + (wave & 1) * 16;   // first q-row of this wave
  float scl2 = __expf(ls[0]) * 0.125f * 1.44269504f;

  const size_t qrow = (size_t)bh * 2048 + base + fr;
  short8 qf0 = *(const short8*)(qb + qrow * 64 + fq * 8);
  short8 qf1 = *(const short8*)(qb + qrow * 64 + 32 + fq * 8);
  // detach qf/scl2 from their defining loads so the compiler doesn't emit
  // conservative in-loop vmcnt waits for them (wait happens here, once).
  asm volatile("" : "+v"(qf0), "+v"(qf1), "+v"(scl2));
  __builtin_amdgcn_sched_barrier(0);

  const bf16* kgb = kb + (size_t)bh * 2048 * 64;
  const bf16* vgb = vt + (size_t)bh * 64 * 2048;

  auto stage = [&](int buf, int t0) {
#pragma unroll
    for (int call = 0; call < 2; ++call) {
      int row = call * 32 + (tid >> 3);
      int sb = ((tid & 7) * 16) ^ ((row & 7) << 4);
      gload_lds16(kgb + (size_t)(t0 + row) * 64 + sb / 2,
                  &sK[buf][call * 2048 + wave * 512]);
    }
#pragma unroll
    for (int call = 0; call < 2; ++call) {
      int row = call * 32 + (tid >> 3);
      int sb = ((tid & 7) * 16) ^ ((row & 7) << 4);
      gload_lds16(vgb + (size_t)row * 2048 + t0 + sb / 2,
                  &sV[buf][call * 2048 + wave * 512]);
    }
  };

  floatx4 oacc[4] = {};
  float mb2[4], lrun[4];
#pragma unroll
  for (int r = 0; r < 4; ++r) { mb2[r] = -INFINITY; lrun[r] = 0.f; }
  const int rowq = base + fq * 4;            // + r
  const int sw = (fr & 7) << 4;
  char* pw = p_lds[wave];
  short8 onesf;
#pragma unroll
  for (int i = 0; i < 8; ++i) onesf[i] = 0x3F80;  // bf16 1.0

  const int tEnd = q0B + 32;
  stage(0, 0);
  stage(1, 64);
  int cur = 0;
  for (int t0 = 0; t0 < tEnd; t0 += 64) {
    if (t0 + 64 < tEnd) wait_vm<4>(); else wait_vm<0>();
    __builtin_amdgcn_s_barrier();
    __builtin_amdgcn_sched_barrier(0);
    if (t0 < myq0 + 32) {  // this wave's letter still active
      const char* sKc = (const char*)sK[cur];
      const char* sVc = (const char*)sV[cur];
      floatx4 sacc[4] = {};
      __builtin_amdgcn_s_setprio(1);
#pragma unroll
      for (int c = 0; c < 4; ++c) {
        int rb = (c * 16 + fr) * 128;
        short8 kf0 = *(const short8*)(sKc + rb + ((fq * 16) ^ sw));
        short8 kf1 = *(const short8*)(sKc + rb + ((64 + fq * 16) ^ sw));
        sacc[c] = __builtin_amdgcn_mfma_f32_16x16x32_bf16(qf0, kf0, sacc[c], 0, 0, 0);
        sacc[c] = __builtin_amdgcn_mfma_f32_16x16x32_bf16(qf1, kf1, sacc[c], 0, 0, 0);
      }
      __builtin_amdgcn_s_setprio(0);
      if (t0 + 63 > rowq) {  // causal mask needed on this substep
#pragma unroll
        for (int c = 0; c < 4; ++c)
#pragma unroll
          for (int r = 0; r < 4; ++r)
            if ((t0 + c * 16 + fr) > (rowq + r)) sacc[c][r] = -1e30f;
      }
      float pl[4];
#pragma unroll
      for (int r = 0; r < 4; ++r)
        pl[r] = fmaxf(fmaxf(sacc[0][r], sacc[1][r]), fmaxf(sacc[2][r], sacc[3][r]));
      float cmax = -INFINITY;
#pragma unroll
      for (int r = 0; r < 4; ++r) cmax = fmaxf(cmax, pl[r] * scl2 - mb2[r]);
      if (!__all(cmax <= 11.5f)) {  // slow path: full row-max + rescale
#pragma unroll
        for (int r = 0; r < 4; ++r) {
          float pm = pl[r];
#pragma unroll
          for (int msk = 1; msk < 16; msk <<= 1) pm = fmaxf(pm, __shfl_xor(pm, msk));
          float mnew = fmaxf(mb2[r], pm * scl2);
          float rs = EXP2(mb2[r] - mnew);
          mb2[r] = mnew;
          lrun[r] *= rs;
#pragma unroll
          for (int d = 0; d < 4; ++d) oacc[d][r] *= rs;
        }
      }
#pragma unroll
      for (int c = 0; c < 4; ++c)
#pragma unroll
        for (int r = 0; r < 4; ++r) {
          union { float f; unsigned int u; } pu;
          pu.f = EXP2(sacc[c][r] * scl2 - mb2[r]);
          int prow = fq * 4 + r;
          *(unsigned short*)(pw + prow * 128 + ((c * 32 + 2 * fr) ^ ((prow & 7) << 4))) =
              (unsigned short)(pu.u >> 16);
        }
      short8 pf0 = *(const short8*)(pw + fr * 128 + ((fq * 16) ^ sw));
      short8 pf1 = *(const short8*)(pw + fr * 128 + ((64 + fq * 16) ^ sw));
      __builtin_amdgcn_s_setprio(1);
      floatx4 tsum = {};
      tsum = __builtin_amdgcn_mfma_f32_16x16x32_bf16(pf0, onesf, tsum, 0, 0, 0);
      tsum = __builtin_amdgcn_mfma_f32_16x16x32_bf16(pf1, onesf, tsum, 0, 0, 0);
#pragma unroll
      for (int d = 0; d < 4; ++d) {
        int rb = (d * 16 + fr) * 128;
        short8 vf0 = *(const short8*)(sVc + rb + ((fq * 16) ^ sw));
        short8 vf1 = *(const short8*)(sVc + rb + ((64 + fq * 16) ^ sw));
        oacc[d] = __builtin_amdgcn_mfma_f32_16x16x32_bf16(pf0, vf0, oacc[d], 0, 0, 0);
        oacc[d] = __builtin_amdgcn_mfma_f32_16x16x32_bf16(pf1, vf1, oacc[d], 0, 0, 0);
      }
      __builtin_amdgcn_s_setprio(0);
#pragma unroll
      for (int r = 0; r < 4; ++r) lrun[r] += tsum[r];
    }
    __builtin_amdgcn_sched_barrier(0);
    __builtin_amdgcn_s_barrier();
    if (t0 + 128 < tEnd) stage(cur, t0 + 128);
    cur ^= 1;
  }
  const int b = bh >> 4, h = bh & 15;
#pragma unroll
  for (int r = 0; r < 4; ++r) {
    float il = 1.0f / lrun[r];
#pragma unroll
    for (int d = 0; d < 4; ++d) {
      size_t o = ((size_t)b * 2048 + rowq + r) * 1024 + h * 64 + d * 16 + fr;
      out[o] = bfbits(oacc[d][r] * il);
    }
  }
}

extern "C" void kernel_launch(void* const* d_in, const int* in_sizes, int n_in,
                              void* d_out, int out_size, void* d_ws, size_t ws_size,
                              hipStream_t stream) {
  (void)in_sizes; (void)n_in; (void)out_size; (void)ws_size;
  const float* x  = (const float*)d_in[0];
  const float* Wq = (const float*)d_in[1];
  const float* bq = (const float*)d_in[2];
  const float* Wk = (const float*)d_in[3];
  const float* bk = (const float*)d_in[4];
  const float* Wv = (const float*)d_in[5];
  const float* bv = (const float*)d_in[6];
  const float* Wo = (const float*)d_in[7];
  const float* bo = (const float*)d_in[8];
  const float* lsc = (const float*)d_in[9];
  // d_in[10] = mask: fixed causal triu(k=1), implemented analytically.

  uint8_t* w = (uint8_t*)d_ws;
  const size_t MB = 1ull << 20;
  bf16* xb   = (bf16*)(w + 0);          // 8 MB
  bf16* wqb  = (bf16*)(w + 8 * MB);     // 2 MB each
  bf16* wkb  = (bf16*)(w + 10 * MB);
  bf16* wvb  = (bf16*)(w + 12 * MB);
  bf16* wob  = (bf16*)(w + 14 * MB);
  bf16* qraw = (bf16*)(w + 16 * MB);    // 8 MB  bf16 [B,S,DIM]
  bf16* kraw = (bf16*)(w + 24 * MB);    // 8 MB
  bf16* qbn  = (bf16*)(w + 32 * MB);    // 8 MB  [B,H,S,64]
  bf16* kbn  = (bf16*)(w + 40 * MB);    // 8 MB
  bf16* vtb  = (bf16*)(w + 48 * MB);    // 8 MB  [B,H,64,S]
  bf16* atb  = (bf16*)(w + 56 * MB);    // 8 MB  [B,S,DIM]
  float* tc  = (float*)(w + 64 * MB);   // 256 KB
  float* ts  = (float*)(w + 64 * MB + 256 * 1024);

  cvt_kernel<<<4096, 256, 0, stream>>>(x, (unsigned short*)xb, Mn * DIMn / 4);
  cvt4_kernel<<<dim3(1024, 4), 256, 0, stream>>>(
      Wq, Wk, Wv, Wo, (unsigned short*)wqb, (unsigned short*)wkb,
      (unsigned short*)wvb, (unsigned short*)wob);
  rope_tab_kernel<<<256, 256, 0, stream>>>(tc, ts);

  qkv_kernel<<<dim3(32, 48), 256, 0, stream>>>(
      xb, wqb, wkb, wvb, bq, bk, bv,
      (unsigned short*)qraw, (unsigned short*)kraw, (unsigned short*)vtb);

  rope_norm_kernel<<<Mn * Hn * 2 / 8, 256, 0, stream>>>(
      (const unsigned short*)qraw, (const unsigned short*)kraw, tc, ts,
      (unsigned short*)qbn, (unsigned short*)kbn);

  attn_kernel<<<1024, 256, 0, stream>>>(qbn, kbn, vtb, lsc,
                                        (unsigned short*)atb);

  gemm_bt_kernel<<<dim3(64, 16), 256, 0, stream>>>(atb, wob, bo, (float*)d_out);
}

// Round 8
// 121.988 us; speedup vs baseline: 1.1026x; 1.1026x over previous
//
#include <hip/hip_runtime.h>
#include <hip/hip_bf16.h>
#include <math.h>

typedef __hip_bfloat16 bf16;
typedef __attribute__((ext_vector_type(8))) short short8;
typedef __attribute__((ext_vector_type(4))) float floatx4;

static constexpr int Bn = 2, Sn = 2048, Hn = 16, DHn = 64, DIMn = 1024;
static constexpr int Mn = Bn * Sn;  // 4096 tokens

#if __has_builtin(__builtin_amdgcn_exp2f)
#define EXP2(x) __builtin_amdgcn_exp2f(x)
#else
#define EXP2(x) exp2f(x)
#endif

__device__ __forceinline__ unsigned short bfbits(float f) {
  union { __hip_bfloat16 h; unsigned short u; } cv;
  cv.h = __float2bfloat16(f);
  return cv.u;
}

__device__ __forceinline__ float bf2f(unsigned short u) {
  union { float f; unsigned int u; } cv;
  cv.u = ((unsigned int)u) << 16;
  return cv.f;
}

// async global->LDS, 16B per lane. dst is wave-uniform base; HW adds lane*16.
__device__ __forceinline__ void gload_lds16(const void* g, void* l) {
  __builtin_amdgcn_global_load_lds(
      (const __attribute__((address_space(1))) uint32_t*)g,
      (__attribute__((address_space(3))) uint32_t*)l, 16, 0, 0);
}

// counted waits (T4). sched_barrier pins per rule #18.
template <int N>
__device__ __forceinline__ void wait_vm() {
  if constexpr (N == 0) asm volatile("s_waitcnt vmcnt(0)" ::: "memory");
  else if constexpr (N == 2) asm volatile("s_waitcnt vmcnt(2)" ::: "memory");
  else if constexpr (N == 3) asm volatile("s_waitcnt vmcnt(3)" ::: "memory");
  else asm volatile("s_waitcnt vmcnt(4)" ::: "memory");
  __builtin_amdgcn_sched_barrier(0);
}

// ---------------- f32 -> bf16 convert (vectorized, 4/thread) ----------------
__global__ void cvt_kernel(const float* __restrict__ src, unsigned short* __restrict__ dst, int n4) {
  int i = blockIdx.x * blockDim.x + threadIdx.x;
  if (i >= n4) return;
  float4 v = ((const float4*)src)[i];
  ushort4 o;
  o.x = bfbits(v.x); o.y = bfbits(v.y); o.z = bfbits(v.z); o.w = bfbits(v.w);
  ((ushort4*)dst)[i] = o;
}

// 4 weight matrices (1M elems each) in one launch: grid (1024, 4)
__global__ void cvt4_kernel(const float* __restrict__ a0, const float* __restrict__ a1,
                            const float* __restrict__ a2, const float* __restrict__ a3,
                            unsigned short* __restrict__ o0, unsigned short* __restrict__ o1,
                            unsigned short* __restrict__ o2, unsigned short* __restrict__ o3) {
  const float* s = (blockIdx.y == 0) ? a0 : (blockIdx.y == 1) ? a1 : (blockIdx.y == 2) ? a2 : a3;
  unsigned short* d = (blockIdx.y == 0) ? o0 : (blockIdx.y == 1) ? o1 : (blockIdx.y == 2) ? o2 : o3;
  int i = blockIdx.x * 256 + threadIdx.x;
  float4 v = ((const float4*)s)[i];
  ushort4 o;
  o.x = bfbits(v.x); o.y = bfbits(v.y); o.z = bfbits(v.z); o.w = bfbits(v.w);
  ((ushort4*)d)[i] = o;
}

// ---------------- RoPE cos/sin tables: [S][32] ----------------
__global__ void rope_tab_kernel(float* __restrict__ tc, float* __restrict__ ts) {
  int t = blockIdx.x * 256 + threadIdx.x;  // 2048*32 = 65536
  int pos = t >> 5, i = t & 31;
  float f = powf(10000.0f, -(float)i * (1.0f / 32.0f));
  float a = (float)pos * f;
  tc[t] = cosf(a);
  ts[t] = sinf(a);
}

// ---------------- fused QKV GEMM + RoPE + l2norm ----------------
// 64x64 tiles, BK=64 (128B LDS rows, XOR-swizzled: attn's zero-conflict
// pattern). grid (64, 48): sel = y>>4, n0 = (y&15)*64 = one full head.
// Wave tiling 16m x 64n so each head row is wave-local -> RoPE+l2norm fused
// in the Q/K epilogue (f32), writing [B,H,S,64] directly.
// V (sel=2): transpose via LDS -> [B,H,64,S].
__global__ __launch_bounds__(256, 4) void qkv_kernel(
    const bf16* __restrict__ A,
    const bf16* __restrict__ Wq, const bf16* __restrict__ Wk, const bf16* __restrict__ Wv,
    const float* __restrict__ bq, const float* __restrict__ bk, const float* __restrict__ bv,
    const float* __restrict__ tc, const float* __restrict__ ts,
    unsigned short* __restrict__ qo, unsigned short* __restrict__ ko,
    unsigned short* __restrict__ vt) {
  __shared__ bf16 smem[16384];  // sA[2][4096] | sB[2][4096]; V reuses as ct
  bf16* sAp = smem;
  bf16* sBp = smem + 8192;
  const int sel = blockIdx.y >> 4;
  const bf16* Bw = (sel == 0) ? Wq : (sel == 1) ? Wk : Wv;
  const float* bias = (sel == 0) ? bq : (sel == 1) ? bk : bv;
  const int tid = threadIdx.x;
  const int lane = tid & 63, wave = tid >> 6;
  const int fr = lane & 15, fq = lane >> 4;
  const int m0 = blockIdx.x * 64, n0 = (blockIdx.y & 15) * 64;

  floatx4 acc[4] = {};  // [ni] ; wave covers rows wave*16..+15, all 64 cols

  // stage one [64 rows][64 k] bf16 tile (128B rows, swz (row&7)<<4) per matrix
  auto stage = [&](int buf, int k0) {
#pragma unroll
    for (int call = 0; call < 2; ++call) {
      int row = call * 32 + (tid >> 3);
      int sb = ((tid & 7) * 16) ^ ((row & 7) << 4);
      gload_lds16(A + (size_t)(m0 + row) * 1024 + k0 + sb / 2,
                  sAp + buf * 4096 + call * 2048 + wave * 512);
    }
#pragma unroll
    for (int call = 0; call < 2; ++call) {
      int row = call * 32 + (tid >> 3);
      int sb = ((tid & 7) * 16) ^ ((row & 7) << 4);
      gload_lds16(Bw + (size_t)(n0 + row) * 1024 + k0 + sb / 2,
                  sBp + buf * 4096 + call * 2048 + wave * 512);
    }
  };

  stage(0, 0);
  stage(1, 64);
  int cur = 0;
  for (int k0 = 0; k0 < 1024; k0 += 64) {
    if (k0 + 64 < 1024) wait_vm<4>(); else wait_vm<0>();
    __builtin_amdgcn_s_barrier();
    __builtin_amdgcn_sched_barrier(0);
    const char* sAc = (const char*)(sAp + cur * 4096);
    const char* sBc = (const char*)(sBp + cur * 4096);
    short8 af[2], bfr[4][2];
    {
      int arow = wave * 16 + fr;
      int asw = (arow & 7) << 4;
#pragma unroll
      for (int kc = 0; kc < 2; ++kc)
        af[kc] = *(const short8*)(sAc + arow * 128 + ((kc * 64 + fq * 16) ^ asw));
    }
#pragma unroll
    for (int ni = 0; ni < 4; ++ni) {
      int brow = ni * 16 + fr;
      int bsw = (brow & 7) << 4;
#pragma unroll
      for (int kc = 0; kc < 2; ++kc)
        bfr[ni][kc] = *(const short8*)(sBc + brow * 128 + ((kc * 64 + fq * 16) ^ bsw));
    }
#pragma unroll
    for (int ni = 0; ni < 4; ++ni)
#pragma unroll
      for (int kc = 0; kc < 2; ++kc)
        acc[ni] = __builtin_amdgcn_mfma_f32_16x16x32_bf16(af[kc], bfr[ni][kc], acc[ni], 0, 0, 0);
    __builtin_amdgcn_sched_barrier(0);
    __builtin_amdgcn_s_barrier();
    if (k0 + 128 < 1024) stage(cur, k0 + 128);
    cur ^= 1;
  }

  if (sel < 2) {
    // fused bias + RoPE + l2norm epilogue (f32), write [B,H,S,64] bf16
    unsigned short* dst = (sel == 0) ? qo : ko;
    const int h = n0 >> 6;
    float bias_d[4];
#pragma unroll
    for (int ni = 0; ni < 4; ++ni) bias_d[ni] = bias[n0 + ni * 16 + fr];
#pragma unroll
    for (int j = 0; j < 4; ++j) {
      int m = m0 + wave * 16 + fq * 4 + j;
      int b = m >> 11, srow = m & 2047;
      float y[4], ss = 0.f;
#pragma unroll
      for (int ni = 0; ni < 4; ++ni) {
        float val = acc[ni][j] + bias_d[ni];
        float prt = __shfl_xor(val, 1);
        int d = ni * 16 + fr;
        int jj = d >> 1;
        float cc = tc[srow * 32 + jj], sn = ts[srow * 32 + jj];
        y[ni] = (d & 1) ? (val * cc + prt * sn) : (val * cc - prt * sn);
        ss += y[ni] * y[ni];
      }
      ss += __shfl_xor(ss, 1);
      ss += __shfl_xor(ss, 2);
      ss += __shfl_xor(ss, 4);
      ss += __shfl_xor(ss, 8);
      float inv = rsqrtf(ss + 1e-6f);
      size_t ob = ((size_t)(b * 16 + h) * 2048 + srow) * 64;
#pragma unroll
      for (int ni = 0; ni < 4; ++ni)
        dst[ob + ni * 16 + fr] = bfbits(y[ni] * inv);
    }
  } else {
    // V: transpose tile through LDS (XOR-swizzled), write coalesced 16B runs.
    char* ct = (char*)smem;  // [nl 64][ml 64] bf16, 128B rows, ^=(nl&7)<<4
#pragma unroll
    for (int ni = 0; ni < 4; ++ni) {
      int nl = ni * 16 + fr;
      float bi = bias[n0 + nl];
#pragma unroll
      for (int j = 0; j < 4; j += 2) {
        int ml = wave * 16 + fq * 4 + j;
        unsigned int u = (unsigned int)bfbits(acc[ni][j] + bi) |
                         ((unsigned int)bfbits(acc[ni][j + 1] + bi) << 16);
        *(unsigned int*)(ct + nl * 128 + ((ml * 2) ^ ((nl & 7) << 4))) = u;
      }
    }
    __syncthreads();
    int nl2 = tid >> 2, ch = tid & 3;
    int dd = nl2;  // n0 is head-aligned: d == nl
    int h = n0 >> 6;
    int b = m0 >> 11, s0 = m0 & 2047;
    unsigned short* orow = vt + (((size_t)b * 16 + h) * 64 + dd) * 2048 + s0;
#pragma unroll
    for (int c = 0; c < 1; ++c) {
      int mb = ch * 16;
      short8 v8a = *(const short8*)(ct + nl2 * 128 + ((mb * 2) ^ ((nl2 & 7) << 4)));
      short8 v8b = *(const short8*)(ct + nl2 * 128 + (((mb + 8) * 2) ^ ((nl2 & 7) << 4)));
      *(short8*)(orow + mb) = v8a;
      *(short8*)(orow + mb + 8) = v8b;
    }
  }
}

// ---------------- Wo GEMM: 64x64 tiles, BK=64, swizzled, f32 out ----------------
__global__ __launch_bounds__(256, 4) void gemm_bt_kernel(
    const bf16* __restrict__ A, const bf16* __restrict__ Bw,
    const float* __restrict__ bias, float* __restrict__ Cf) {
  __shared__ bf16 smem[16384];  // sA[2][4096] | sB[2][4096]
  bf16* sAp = smem;
  bf16* sBp = smem + 8192;
  const int tid = threadIdx.x;
  const int lane = tid & 63, wave = tid >> 6;
  const int fr = lane & 15, fq = lane >> 4;
  const int m0 = blockIdx.x * 64, n0 = blockIdx.y * 64;

  floatx4 acc[4] = {};

  auto stage = [&](int buf, int k0) {
#pragma unroll
    for (int call = 0; call < 2; ++call) {
      int row = call * 32 + (tid >> 3);
      int sb = ((tid & 7) * 16) ^ ((row & 7) << 4);
      gload_lds16(A + (size_t)(m0 + row) * 1024 + k0 + sb / 2,
                  sAp + buf * 4096 + call * 2048 + wave * 512);
    }
#pragma unroll
    for (int call = 0; call < 2; ++call) {
      int row = call * 32 + (tid >> 3);
      int sb = ((tid & 7) * 16) ^ ((row & 7) << 4);
      gload_lds16(Bw + (size_t)(n0 + row) * 1024 + k0 + sb / 2,
                  sBp + buf * 4096 + call * 2048 + wave * 512);
    }
  };

  stage(0, 0);
  stage(1, 64);
  int cur = 0;
  for (int k0 = 0; k0 < 1024; k0 += 64) {
    if (k0 + 64 < 1024) wait_vm<4>(); else wait_vm<0>();
    __builtin_amdgcn_s_barrier();
    __builtin_amdgcn_sched_barrier(0);
    const char* sAc = (const char*)(sAp + cur * 4096);
    const char* sBc = (const char*)(sBp + cur * 4096);
    short8 af[2], bfr[4][2];
    {
      int arow = wave * 16 + fr;
      int asw = (arow & 7) << 4;
#pragma unroll
      for (int kc = 0; kc < 2; ++kc)
        af[kc] = *(const short8*)(sAc + arow * 128 + ((kc * 64 + fq * 16) ^ asw));
    }
#pragma unroll
    for (int ni = 0; ni < 4; ++ni) {
      int brow = ni * 16 + fr;
      int bsw = (brow & 7) << 4;
#pragma unroll
      for (int kc = 0; kc < 2; ++kc)
        bfr[ni][kc] = *(const short8*)(sBc + brow * 128 + ((kc * 64 + fq * 16) ^ bsw));
    }
#pragma unroll
    for (int ni = 0; ni < 4; ++ni)
#pragma unroll
      for (int kc = 0; kc < 2; ++kc)
        acc[ni] = __builtin_amdgcn_mfma_f32_16x16x32_bf16(af[kc], bfr[ni][kc], acc[ni], 0, 0, 0);
    __builtin_amdgcn_sched_barrier(0);
    __builtin_amdgcn_s_barrier();
    if (k0 + 128 < 1024) stage(cur, k0 + 128);
    cur ^= 1;
  }

#pragma unroll
  for (int ni = 0; ni < 4; ++ni) {
    int n = n0 + ni * 16 + fr;
    float bi = bias[n];
#pragma unroll
    for (int j = 0; j < 4; ++j) {
      int m = m0 + wave * 16 + fq * 4 + j;
      Cf[(size_t)m * 1024 + n] = acc[ni][j] + bi;
    }
  }
}

// ---------------- causal flash attention, split-letter paired q-tiles ----------------
// grid 1024 (1D). Balanced dispatch permutation: co-resident blocks (ids
// differing by 256) get xq values {j, 31-j} so per-CU iteration sums are
// constant. Waves 0,1 own q-tile xq; waves 2,3 own 63-xq. KVBLK=64 dbuf,
// counted vmcnt. LDS 40KB -> 4 blocks/CU.
__global__ __launch_bounds__(256, 4) void attn_kernel(
    const bf16* __restrict__ qb, const bf16* __restrict__ kb, const bf16* __restrict__ vt,
    const float* __restrict__ ls, unsigned short* __restrict__ out) {
  __shared__ bf16 sK[2][64 * 64];   // [kv][d], 128B rows, swz (row&7)<<4
  __shared__ bf16 sV[2][64 * 64];   // [d][kv], 128B rows, swz (row&7)<<4
  __shared__ char p_lds[4][2048];   // per wave: 16x64 bf16, swz (prow&7)<<4
  const int bid = blockIdx.x;
  const int rr4 = bid >> 8, g = bid & 255, jj = g & 31;
  const int xq = (rr4 & 1) ? (31 - jj) : jj;
  const int bh = (g >> 5) + 8 * rr4;
  const int q0A = xq * 32, q0B = (63 - xq) * 32;
  const int tid = threadIdx.x;
  const int lane = tid & 63, wave = tid >> 6;
  const int fr = lane & 15, fq = lane >> 4;
  const int myq0 = (wave >= 2) ? q0B : q0A;
  const int base = myq0 + (wave & 1) * 16;   // first q-row of this wave
  float scl2 = __expf(ls[0]) * 0.125f * 1.44269504f;

  const size_t qrow = (size_t)bh * 2048 + base + fr;
  short8 qf0 = *(const short8*)(qb + qrow * 64 + fq * 8);
  short8 qf1 = *(const short8*)(qb + qrow * 64 + 32 + fq * 8);
  // detach qf/scl2 from their defining loads so the compiler doesn't emit
  // conservative in-loop vmcnt waits for them (wait happens here, once).
  asm volatile("" : "+v"(qf0), "+v"(qf1), "+v"(scl2));
  __builtin_amdgcn_sched_barrier(0);

  const bf16* kgb = kb + (size_t)bh * 2048 * 64;
  const bf16* vgb = vt + (size_t)bh * 64 * 2048;

  auto stage = [&](int buf, int t0) {
#pragma unroll
    for (int call = 0; call < 2; ++call) {
      int row = call * 32 + (tid >> 3);
      int sb = ((tid & 7) * 16) ^ ((row & 7) << 4);
      gload_lds16(kgb + (size_t)(t0 + row) * 64 + sb / 2,
                  &sK[buf][call * 2048 + wave * 512]);
    }
#pragma unroll
    for (int call = 0; call < 2; ++call) {
      int row = call * 32 + (tid >> 3);
      int sb = ((tid & 7) * 16) ^ ((row & 7) << 4);
      gload_lds16(vgb + (size_t)row * 2048 + t0 + sb / 2,
                  &sV[buf][call * 2048 + wave * 512]);
    }
  };

  floatx4 oacc[4] = {};
  float mb2[4], lrun[4];
#pragma unroll
  for (int r = 0; r < 4; ++r) { mb2[r] = -INFINITY; lrun[r] = 0.f; }
  const int rowq = base + fq * 4;            // + r
  const int sw = (fr & 7) << 4;
  char* pw = p_lds[wave];
  short8 onesf;
#pragma unroll
  for (int i = 0; i < 8; ++i) onesf[i] = 0x3F80;  // bf16 1.0

  const int tEnd = q0B + 32;
  stage(0, 0);
  stage(1, 64);
  int cur = 0;
  for (int t0 = 0; t0 < tEnd; t0 += 64) {
    if (t0 + 64 < tEnd) wait_vm<4>(); else wait_vm<0>();
    __builtin_amdgcn_s_barrier();
    __builtin_amdgcn_sched_barrier(0);
    if (t0 < myq0 + 32) {  // this wave's letter still active
      const char* sKc = (const char*)sK[cur];
      const char* sVc = (const char*)sV[cur];
      floatx4 sacc[4] = {};
      __builtin_amdgcn_s_setprio(1);
#pragma unroll
      for (int c = 0; c < 4; ++c) {
        int rb = (c * 16 + fr) * 128;
        short8 kf0 = *(const short8*)(sKc + rb + ((fq * 16) ^ sw));
        short8 kf1 = *(const short8*)(sKc + rb + ((64 + fq * 16) ^ sw));
        sacc[c] = __builtin_amdgcn_mfma_f32_16x16x32_bf16(qf0, kf0, sacc[c], 0, 0, 0);
        sacc[c] = __builtin_amdgcn_mfma_f32_16x16x32_bf16(qf1, kf1, sacc[c], 0, 0, 0);
      }
      __builtin_amdgcn_s_setprio(0);
      if (t0 + 63 > rowq) {  // causal mask needed on this substep
#pragma unroll
        for (int c = 0; c < 4; ++c)
#pragma unroll
          for (int r = 0; r < 4; ++r)
            if ((t0 + c * 16 + fr) > (rowq + r)) sacc[c][r] = -1e30f;
      }
      float pl[4];
#pragma unroll
      for (int r = 0; r < 4; ++r)
        pl[r] = fmaxf(fmaxf(sacc[0][r], sacc[1][r]), fmaxf(sacc[2][r], sacc[3][r]));
      float cmax = -INFINITY;
#pragma unroll
      for (int r = 0; r < 4; ++r) cmax = fmaxf(cmax, pl[r] * scl2 - mb2[r]);
      if (!__all(cmax <= 11.5f)) {  // slow path: full row-max + rescale
#pragma unroll
        for (int r = 0; r < 4; ++r) {
          float pm = pl[r];
#pragma unroll
          for (int msk = 1; msk < 16; msk <<= 1) pm = fmaxf(pm, __shfl_xor(pm, msk));
          float mnew = fmaxf(mb2[r], pm * scl2);
          float rs = EXP2(mb2[r] - mnew);
          mb2[r] = mnew;
          lrun[r] *= rs;
#pragma unroll
          for (int d = 0; d < 4; ++d) oacc[d][r] *= rs;
        }
      }
#pragma unroll
      for (int c = 0; c < 4; ++c)
#pragma unroll
        for (int r = 0; r < 4; ++r) {
          union { float f; unsigned int u; } pu;
          pu.f = EXP2(sacc[c][r] * scl2 - mb2[r]);
          int prow = fq * 4 + r;
          *(unsigned short*)(pw + prow * 128 + ((c * 32 + 2 * fr) ^ ((prow & 7) << 4))) =
              (unsigned short)(pu.u >> 16);
        }
      short8 pf0 = *(const short8*)(pw + fr * 128 + ((fq * 16) ^ sw));
      short8 pf1 = *(const short8*)(pw + fr * 128 + ((64 + fq * 16) ^ sw));
      __builtin_amdgcn_s_setprio(1);
      floatx4 tsum = {};
      tsum = __builtin_amdgcn_mfma_f32_16x16x32_bf16(pf0, onesf, tsum, 0, 0, 0);
      tsum = __builtin_amdgcn_mfma_f32_16x16x32_bf16(pf1, onesf, tsum, 0, 0, 0);
#pragma unroll
      for (int d = 0; d < 4; ++d) {
        int rb = (d * 16 + fr) * 128;
        short8 vf0 = *(const short8*)(sVc + rb + ((fq * 16) ^ sw));
        short8 vf1 = *(const short8*)(sVc + rb + ((64 + fq * 16) ^ sw));
        oacc[d] = __builtin_amdgcn_mfma_f32_16x16x32_bf16(pf0, vf0, oacc[d], 0, 0, 0);
        oacc[d] = __builtin_amdgcn_mfma_f32_16x16x32_bf16(pf1, vf1, oacc[d], 0, 0, 0);
      }
      __builtin_amdgcn_s_setprio(0);
#pragma unroll
      for (int r = 0; r < 4; ++r) lrun[r] += tsum[r];
    }
    __builtin_amdgcn_sched_barrier(0);
    __builtin_amdgcn_s_barrier();
    if (t0 + 128 < tEnd) stage(cur, t0 + 128);
    cur ^= 1;
  }
  const int b = bh >> 4, h = bh & 15;
#pragma unroll
  for (int r = 0; r < 4; ++r) {
    float il = 1.0f / lrun[r];
#pragma unroll
    for (int d = 0; d < 4; ++d) {
      size_t o = ((size_t)b * 2048 + rowq + r) * 1024 + h * 64 + d * 16 + fr;
      out[o] = bfbits(oacc[d][r] * il);
    }
  }
}

extern "C" void kernel_launch(void* const* d_in, const int* in_sizes, int n_in,
                              void* d_out, int out_size, void* d_ws, size_t ws_size,
                              hipStream_t stream) {
  (void)in_sizes; (void)n_in; (void)out_size; (void)ws_size;
  const float* x  = (const float*)d_in[0];
  const float* Wq = (const float*)d_in[1];
  const float* bq = (const float*)d_in[2];
  const float* Wk = (const float*)d_in[3];
  const float* bk = (const float*)d_in[4];
  const float* Wv = (const float*)d_in[5];
  const float* bv = (const float*)d_in[6];
  const float* Wo = (const float*)d_in[7];
  const float* bo = (const float*)d_in[8];
  const float* lsc = (const float*)d_in[9];
  // d_in[10] = mask: fixed causal triu(k=1), implemented analytically.

  uint8_t* w = (uint8_t*)d_ws;
  const size_t MB = 1ull << 20;
  bf16* xb   = (bf16*)(w + 0);          // 8 MB
  bf16* wqb  = (bf16*)(w + 8 * MB);     // 2 MB each
  bf16* wkb  = (bf16*)(w + 10 * MB);
  bf16* wvb  = (bf16*)(w + 12 * MB);
  bf16* wob  = (bf16*)(w + 14 * MB);
  bf16* qbn  = (bf16*)(w + 16 * MB);    // 8 MB  [B,H,S,64]
  bf16* kbn  = (bf16*)(w + 24 * MB);    // 8 MB
  bf16* vtb  = (bf16*)(w + 32 * MB);    // 8 MB  [B,H,64,S]
  bf16* atb  = (bf16*)(w + 40 * MB);    // 8 MB  [B,S,DIM]
  float* tc  = (float*)(w + 48 * MB);   // 256 KB
  float* ts  = (float*)(w + 48 * MB + 256 * 1024);

  cvt_kernel<<<4096, 256, 0, stream>>>(x, (unsigned short*)xb, Mn * DIMn / 4);
  cvt4_kernel<<<dim3(1024, 4), 256, 0, stream>>>(
      Wq, Wk, Wv, Wo, (unsigned short*)wqb, (unsigned short*)wkb,
      (unsigned short*)wvb, (unsigned short*)wob);
  rope_tab_kernel<<<256, 256, 0, stream>>>(tc, ts);

  qkv_kernel<<<dim3(64, 48), 256, 0, stream>>>(
      xb, wqb, wkb, wvb, bq, bk, bv, tc, ts,
      (unsigned short*)qbn, (unsigned short*)kbn, (unsigned short*)vtb);

  attn_kernel<<<1024, 256, 0, stream>>>(qbn, kbn, vtb, lsc,
                                        (unsigned short*)atb);

  gemm_bt_kernel<<<dim3(64, 16), 256, 0, stream>>>(atb, wob, bo, (float*)d_out);
}

// Round 9
// 117.188 us; speedup vs baseline: 1.1478x; 1.0410x over previous
//
#include <hip/hip_runtime.h>
#include <hip/hip_bf16.h>
#include <math.h>

typedef __hip_bfloat16 bf16;
typedef __attribute__((ext_vector_type(8))) short short8;
typedef __attribute__((ext_vector_type(4))) float floatx4;

static constexpr int Bn = 2, Sn = 2048, Hn = 16, DHn = 64, DIMn = 1024;
static constexpr int Mn = Bn * Sn;  // 4096 tokens

#if __has_builtin(__builtin_amdgcn_exp2f)
#define EXP2(x) __builtin_amdgcn_exp2f(x)
#else
#define EXP2(x) exp2f(x)
#endif

__device__ __forceinline__ unsigned short bfbits(float f) {
  union { __hip_bfloat16 h; unsigned short u; } cv;
  cv.h = __float2bfloat16(f);
  return cv.u;
}

__device__ __forceinline__ float bf2f(unsigned short u) {
  union { float f; unsigned int u; } cv;
  cv.u = ((unsigned int)u) << 16;
  return cv.f;
}

// async global->LDS, 16B per lane. dst is wave-uniform base; HW adds lane*16.
__device__ __forceinline__ void gload_lds16(const void* g, void* l) {
  __builtin_amdgcn_global_load_lds(
      (const __attribute__((address_space(1))) uint32_t*)g,
      (__attribute__((address_space(3))) uint32_t*)l, 16, 0, 0);
}

// counted waits (T4). sched_barrier pins per rule #18.
template <int N>
__device__ __forceinline__ void wait_vm() {
  if constexpr (N == 0) asm volatile("s_waitcnt vmcnt(0)" ::: "memory");
  else if constexpr (N == 2) asm volatile("s_waitcnt vmcnt(2)" ::: "memory");
  else if constexpr (N == 3) asm volatile("s_waitcnt vmcnt(3)" ::: "memory");
  else asm volatile("s_waitcnt vmcnt(4)" ::: "memory");
  __builtin_amdgcn_sched_barrier(0);
}

// ---------------- fused prep: x->bf16 | 4 weights->bf16 | rope tables ----------------
// grid 8448: [0,4096) x, [4096,8192) weights, [8192,8448) rope tables.
__global__ void prep_kernel(const float* __restrict__ x,
                            const float* __restrict__ a0, const float* __restrict__ a1,
                            const float* __restrict__ a2, const float* __restrict__ a3,
                            unsigned short* __restrict__ xo,
                            unsigned short* __restrict__ o0, unsigned short* __restrict__ o1,
                            unsigned short* __restrict__ o2, unsigned short* __restrict__ o3,
                            float* __restrict__ tc, float* __restrict__ ts) {
  const int bid = blockIdx.x;
  if (bid < 8192) {
    const float* s;
    unsigned short* d;
    int i;
    if (bid < 4096) {
      s = x; d = xo; i = bid * 256 + threadIdx.x;
    } else {
      int wsel = (bid - 4096) >> 10;
      s = (wsel == 0) ? a0 : (wsel == 1) ? a1 : (wsel == 2) ? a2 : a3;
      d = (wsel == 0) ? o0 : (wsel == 1) ? o1 : (wsel == 2) ? o2 : o3;
      i = ((bid - 4096) & 1023) * 256 + threadIdx.x;
    }
    float4 v = ((const float4*)s)[i];
    ushort4 o;
    o.x = bfbits(v.x); o.y = bfbits(v.y); o.z = bfbits(v.z); o.w = bfbits(v.w);
    ((ushort4*)d)[i] = o;
  } else {
    int t = (bid - 8192) * 256 + threadIdx.x;  // 2048*32 = 65536
    int pos = t >> 5, i = t & 31;
    float f = powf(10000.0f, -(float)i * (1.0f / 32.0f));
    float a = (float)pos * f;
    tc[t] = cosf(a);
    ts[t] = sinf(a);
  }
}

// ---------------- fused QKV GEMM + RoPE + l2norm ----------------
// 64x64 tiles, BK=64 (128B LDS rows, XOR-swizzled: zero-conflict pattern).
// grid (64, 48): sel = y>>4, n0 = (y&15)*64 = one full head.
// Wave tiling 16m x 64n so each head row is wave-local -> RoPE+l2norm fused
// in the Q/K epilogue (f32), writing [B,H,S,64] directly.
// V (sel=2): transpose via LDS -> [B,H,64,S].
__global__ __launch_bounds__(256, 4) void qkv_kernel(
    const bf16* __restrict__ A,
    const bf16* __restrict__ Wq, const bf16* __restrict__ Wk, const bf16* __restrict__ Wv,
    const float* __restrict__ bq, const float* __restrict__ bk, const float* __restrict__ bv,
    const float* __restrict__ tc, const float* __restrict__ ts,
    unsigned short* __restrict__ qo, unsigned short* __restrict__ ko,
    unsigned short* __restrict__ vt) {
  __shared__ bf16 smem[16384];  // sA[2][4096] | sB[2][4096]; V reuses as ct
  bf16* sAp = smem;
  bf16* sBp = smem + 8192;
  const int sel = blockIdx.y >> 4;
  const bf16* Bw = (sel == 0) ? Wq : (sel == 1) ? Wk : Wv;
  const float* bias = (sel == 0) ? bq : (sel == 1) ? bk : bv;
  const int tid = threadIdx.x;
  const int lane = tid & 63, wave = tid >> 6;
  const int fr = lane & 15, fq = lane >> 4;
  const int m0 = blockIdx.x * 64, n0 = (blockIdx.y & 15) * 64;

  floatx4 acc[4] = {};  // [ni] ; wave covers rows wave*16..+15, all 64 cols

  // stage one [64 rows][64 k] bf16 tile (128B rows, swz (row&7)<<4) per matrix
  auto stage = [&](int buf, int k0) {
#pragma unroll
    for (int call = 0; call < 2; ++call) {
      int row = call * 32 + (tid >> 3);
      int sb = ((tid & 7) * 16) ^ ((row & 7) << 4);
      gload_lds16(A + (size_t)(m0 + row) * 1024 + k0 + sb / 2,
                  sAp + buf * 4096 + call * 2048 + wave * 512);
    }
#pragma unroll
    for (int call = 0; call < 2; ++call) {
      int row = call * 32 + (tid >> 3);
      int sb = ((tid & 7) * 16) ^ ((row & 7) << 4);
      gload_lds16(Bw + (size_t)(n0 + row) * 1024 + k0 + sb / 2,
                  sBp + buf * 4096 + call * 2048 + wave * 512);
    }
  };

  stage(0, 0);
  stage(1, 64);
  int cur = 0;
  for (int k0 = 0; k0 < 1024; k0 += 64) {
    if (k0 + 64 < 1024) wait_vm<4>(); else wait_vm<0>();
    __builtin_amdgcn_s_barrier();
    __builtin_amdgcn_sched_barrier(0);
    const char* sAc = (const char*)(sAp + cur * 4096);
    const char* sBc = (const char*)(sBp + cur * 4096);
    short8 af[2], bfr[4][2];
    {
      int arow = wave * 16 + fr;
      int asw = (arow & 7) << 4;
#pragma unroll
      for (int kc = 0; kc < 2; ++kc)
        af[kc] = *(const short8*)(sAc + arow * 128 + ((kc * 64 + fq * 16) ^ asw));
    }
#pragma unroll
    for (int ni = 0; ni < 4; ++ni) {
      int brow = ni * 16 + fr;
      int bsw = (brow & 7) << 4;
#pragma unroll
      for (int kc = 0; kc < 2; ++kc)
        bfr[ni][kc] = *(const short8*)(sBc + brow * 128 + ((kc * 64 + fq * 16) ^ bsw));
    }
#pragma unroll
    for (int ni = 0; ni < 4; ++ni)
#pragma unroll
      for (int kc = 0; kc < 2; ++kc)
        acc[ni] = __builtin_amdgcn_mfma_f32_16x16x32_bf16(af[kc], bfr[ni][kc], acc[ni], 0, 0, 0);
    __builtin_amdgcn_sched_barrier(0);
    __builtin_amdgcn_s_barrier();
    if (k0 + 128 < 1024) stage(cur, k0 + 128);
    cur ^= 1;
  }

  if (sel < 2) {
    // fused bias + RoPE + l2norm epilogue (f32), write [B,H,S,64] bf16
    unsigned short* dst = (sel == 0) ? qo : ko;
    const int h = n0 >> 6;
    float bias_d[4];
#pragma unroll
    for (int ni = 0; ni < 4; ++ni) bias_d[ni] = bias[n0 + ni * 16 + fr];
#pragma unroll
    for (int j = 0; j < 4; ++j) {
      int m = m0 + wave * 16 + fq * 4 + j;
      int b = m >> 11, srow = m & 2047;
      float y[4], ss = 0.f;
#pragma unroll
      for (int ni = 0; ni < 4; ++ni) {
        float val = acc[ni][j] + bias_d[ni];
        float prt = __shfl_xor(val, 1);
        int d = ni * 16 + fr;
        int jj = d >> 1;
        float cc = tc[srow * 32 + jj], sn = ts[srow * 32 + jj];
        y[ni] = (d & 1) ? (val * cc + prt * sn) : (val * cc - prt * sn);
        ss += y[ni] * y[ni];
      }
      ss += __shfl_xor(ss, 1);
      ss += __shfl_xor(ss, 2);
      ss += __shfl_xor(ss, 4);
      ss += __shfl_xor(ss, 8);
      float inv = rsqrtf(ss + 1e-6f);
      size_t ob = ((size_t)(b * 16 + h) * 2048 + srow) * 64;
#pragma unroll
      for (int ni = 0; ni < 4; ++ni)
        dst[ob + ni * 16 + fr] = bfbits(y[ni] * inv);
    }
  } else {
    // V: transpose tile through LDS (XOR-swizzled), write coalesced 16B runs.
    char* ct = (char*)smem;  // [nl 64][ml 64] bf16, 128B rows, ^=(nl&7)<<4
#pragma unroll
    for (int ni = 0; ni < 4; ++ni) {
      int nl = ni * 16 + fr;
      float bi = bias[n0 + nl];
#pragma unroll
      for (int j = 0; j < 4; j += 2) {
        int ml = wave * 16 + fq * 4 + j;
        unsigned int u = (unsigned int)bfbits(acc[ni][j] + bi) |
                         ((unsigned int)bfbits(acc[ni][j + 1] + bi) << 16);
        *(unsigned int*)(ct + nl * 128 + ((ml * 2) ^ ((nl & 7) << 4))) = u;
      }
    }
    __syncthreads();
    int nl2 = tid >> 2, ch = tid & 3;
    int dd = nl2;  // n0 is head-aligned: d == nl
    int h = n0 >> 6;
    int b = m0 >> 11, s0 = m0 & 2047;
    unsigned short* orow = vt + (((size_t)b * 16 + h) * 64 + dd) * 2048 + s0;
    {
      int mb = ch * 16;
      short8 v8a = *(const short8*)(ct + nl2 * 128 + ((mb * 2) ^ ((nl2 & 7) << 4)));
      short8 v8b = *(const short8*)(ct + nl2 * 128 + (((mb + 8) * 2) ^ ((nl2 & 7) << 4)));
      *(short8*)(orow + mb) = v8a;
      *(short8*)(orow + mb + 8) = v8b;
    }
  }
}

// ---------------- Wo GEMM: 64x64 tiles, BK=64, swizzled, f32 out ----------------
__global__ __launch_bounds__(256, 4) void gemm_bt_kernel(
    const bf16* __restrict__ A, const bf16* __restrict__ Bw,
    const float* __restrict__ bias, float* __restrict__ Cf) {
  __shared__ bf16 smem[16384];  // sA[2][4096] | sB[2][4096]
  bf16* sAp = smem;
  bf16* sBp = smem + 8192;
  const int tid = threadIdx.x;
  const int lane = tid & 63, wave = tid >> 6;
  const int fr = lane & 15, fq = lane >> 4;
  const int m0 = blockIdx.x * 64, n0 = blockIdx.y * 64;

  floatx4 acc[4] = {};

  auto stage = [&](int buf, int k0) {
#pragma unroll
    for (int call = 0; call < 2; ++call) {
      int row = call * 32 + (tid >> 3);
      int sb = ((tid & 7) * 16) ^ ((row & 7) << 4);
      gload_lds16(A + (size_t)(m0 + row) * 1024 + k0 + sb / 2,
                  sAp + buf * 4096 + call * 2048 + wave * 512);
    }
#pragma unroll
    for (int call = 0; call < 2; ++call) {
      int row = call * 32 + (tid >> 3);
      int sb = ((tid & 7) * 16) ^ ((row & 7) << 4);
      gload_lds16(Bw + (size_t)(n0 + row) * 1024 + k0 + sb / 2,
                  sBp + buf * 4096 + call * 2048 + wave * 512);
    }
  };

  stage(0, 0);
  stage(1, 64);
  int cur = 0;
  for (int k0 = 0; k0 < 1024; k0 += 64) {
    if (k0 + 64 < 1024) wait_vm<4>(); else wait_vm<0>();
    __builtin_amdgcn_s_barrier();
    __builtin_amdgcn_sched_barrier(0);
    const char* sAc = (const char*)(sAp + cur * 4096);
    const char* sBc = (const char*)(sBp + cur * 4096);
    short8 af[2], bfr[4][2];
    {
      int arow = wave * 16 + fr;
      int asw = (arow & 7) << 4;
#pragma unroll
      for (int kc = 0; kc < 2; ++kc)
        af[kc] = *(const short8*)(sAc + arow * 128 + ((kc * 64 + fq * 16) ^ asw));
    }
#pragma unroll
    for (int ni = 0; ni < 4; ++ni) {
      int brow = ni * 16 + fr;
      int bsw = (brow & 7) << 4;
#pragma unroll
      for (int kc = 0; kc < 2; ++kc)
        bfr[ni][kc] = *(const short8*)(sBc + brow * 128 + ((kc * 64 + fq * 16) ^ bsw));
    }
#pragma unroll
    for (int ni = 0; ni < 4; ++ni)
#pragma unroll
      for (int kc = 0; kc < 2; ++kc)
        acc[ni] = __builtin_amdgcn_mfma_f32_16x16x32_bf16(af[kc], bfr[ni][kc], acc[ni], 0, 0, 0);
    __builtin_amdgcn_sched_barrier(0);
    __builtin_amdgcn_s_barrier();
    if (k0 + 128 < 1024) stage(cur, k0 + 128);
    cur ^= 1;
  }

#pragma unroll
  for (int ni = 0; ni < 4; ++ni) {
    int n = n0 + ni * 16 + fr;
    float bi = bias[n];
#pragma unroll
    for (int j = 0; j < 4; ++j) {
      int m = m0 + wave * 16 + fq * 4 + j;
      Cf[(size_t)m * 1024 + n] = acc[ni][j] + bi;
    }
  }
}

// ---------------- causal flash attention, split-letter paired q-tiles ----------------
// grid 1024 (1D). Balanced dispatch permutation (iteration counts) + letter
// assignment XOR'd with bid&1 so each SIMD hosts a mix of short-letter and
// long-letter waves across its resident blocks (wave i always lands on SIMD
// i; without the flip, SIMD0/1 held only early-idling letter-A waves).
// KVBLK=64 dbuf, counted vmcnt. LDS 40KB -> 4 blocks/CU.
__global__ __launch_bounds__(256, 4) void attn_kernel(
    const bf16* __restrict__ qb, const bf16* __restrict__ kb, const bf16* __restrict__ vt,
    const float* __restrict__ ls, unsigned short* __restrict__ out) {
  __shared__ bf16 sK[2][64 * 64];   // [kv][d], 128B rows, swz (row&7)<<4
  __shared__ bf16 sV[2][64 * 64];   // [d][kv], 128B rows, swz (row&7)<<4
  __shared__ char p_lds[4][2048];   // per wave: 16x64 bf16, swz (prow&7)<<4
  const int bid = blockIdx.x;
  const int rr4 = bid >> 8, g = bid & 255, jj = g & 31;
  const int xq = (rr4 & 1) ? (31 - jj) : jj;
  const int bh = (g >> 5) + 8 * rr4;
  const int q0A = xq * 32, q0B = (63 - xq) * 32;
  const int tid = threadIdx.x;
  const int lane = tid & 63, wave = tid >> 6;
  const int fr = lane & 15, fq = lane >> 4;
  const int myq0 = ((((wave >> 1) ^ bid) & 1)) ? q0B : q0A;  // letter flip
  const int base = myq0 + (wave & 1) * 16;   // first q-row of this wave
  float scl2 = __expf(ls[0]) * 0.125f * 1.44269504f;

  const size_t qrow = (size_t)bh * 2048 + base + fr;
  short8 qf0 = *(const short8*)(qb + qrow * 64 + fq * 8);
  short8 qf1 = *(const short8*)(qb + qrow * 64 + 32 + fq * 8);
  // detach qf/scl2 from their defining loads so the compiler doesn't emit
  // conservative in-loop vmcnt waits for them (wait happens here, once).
  asm volatile("" : "+v"(qf0), "+v"(qf1), "+v"(scl2));
  __builtin_amdgcn_sched_barrier(0);

  const bf16* kgb = kb + (size_t)bh * 2048 * 64;
  const bf16* vgb = vt + (size_t)bh * 64 * 2048;

  auto stage = [&](int buf, int t0) {
#pragma unroll
    for (int call = 0; call < 2; ++call) {
      int row = call * 32 + (tid >> 3);
      int sb = ((tid & 7) * 16) ^ ((row & 7) << 4);
      gload_lds16(kgb + (size_t)(t0 + row) * 64 + sb / 2,
                  &sK[buf][call * 2048 + wave * 512]);
    }
#pragma unroll
    for (int call = 0; call < 2; ++call) {
      int row = call * 32 + (tid >> 3);
      int sb = ((tid & 7) * 16) ^ ((row & 7) << 4);
      gload_lds16(vgb + (size_t)row * 2048 + t0 + sb / 2,
                  &sV[buf][call * 2048 + wave * 512]);
    }
  };

  floatx4 oacc[4] = {};
  float mb2[4], lrun[4];
#pragma unroll
  for (int r = 0; r < 4; ++r) { mb2[r] = -INFINITY; lrun[r] = 0.f; }
  const int rowq = base + fq * 4;            // + r
  const int sw = (fr & 7) << 4;
  char* pw = p_lds[wave];
  short8 onesf;
#pragma unroll
  for (int i = 0; i < 8; ++i) onesf[i] = 0x3F80;  // bf16 1.0

  const int tEnd = q0B + 32;
  stage(0, 0);
  stage(1, 64);
  int cur = 0;
  for (int t0 = 0; t0 < tEnd; t0 += 64) {
    if (t0 + 64 < tEnd) wait_vm<4>(); else wait_vm<0>();
    __builtin_amdgcn_s_barrier();
    __builtin_amdgcn_sched_barrier(0);
    if (t0 < myq0 + 32) {  // this wave's letter still active
      const char* sKc = (const char*)sK[cur];
      const char* sVc = (const char*)sV[cur];
      floatx4 sacc[4] = {};
      __builtin_amdgcn_s_setprio(1);
#pragma unroll
      for (int c = 0; c < 4; ++c) {
        int rb = (c * 16 + fr) * 128;
        short8 kf0 = *(const short8*)(sKc + rb + ((fq * 16) ^ sw));
        short8 kf1 = *(const short8*)(sKc + rb + ((64 + fq * 16) ^ sw));
        sacc[c] = __builtin_amdgcn_mfma_f32_16x16x32_bf16(qf0, kf0, sacc[c], 0, 0, 0);
        sacc[c] = __builtin_amdgcn_mfma_f32_16x16x32_bf16(qf1, kf1, sacc[c], 0, 0, 0);
      }
      __builtin_amdgcn_s_setprio(0);
      if (t0 + 63 > rowq) {  // causal mask needed on this substep
#pragma unroll
        for (int c = 0; c < 4; ++c)
#pragma unroll
          for (int r = 0; r < 4; ++r)
            if ((t0 + c * 16 + fr) > (rowq + r)) sacc[c][r] = -1e30f;
      }
      float pl[4];
#pragma unroll
      for (int r = 0; r < 4; ++r)
        pl[r] = fmaxf(fmaxf(sacc[0][r], sacc[1][r]), fmaxf(sacc[2][r], sacc[3][r]));
      float cmax = -INFINITY;
#pragma unroll
      for (int r = 0; r < 4; ++r) cmax = fmaxf(cmax, pl[r] * scl2 - mb2[r]);
      if (!__all(cmax <= 11.5f)) {  // slow path: full row-max + rescale
#pragma unroll
        for (int r = 0; r < 4; ++r) {
          float pm = pl[r];
#pragma unroll
          for (int msk = 1; msk < 16; msk <<= 1) pm = fmaxf(pm, __shfl_xor(pm, msk));
          float mnew = fmaxf(mb2[r], pm * scl2);
          float rs = EXP2(mb2[r] - mnew);
          mb2[r] = mnew;
          lrun[r] *= rs;
#pragma unroll
          for (int d = 0; d < 4; ++d) oacc[d][r] *= rs;
        }
      }
#pragma unroll
      for (int c = 0; c < 4; ++c)
#pragma unroll
        for (int r = 0; r < 4; ++r) {
          union { float f; unsigned int u; } pu;
          pu.f = EXP2(sacc[c][r] * scl2 - mb2[r]);
          int prow = fq * 4 + r;
          *(unsigned short*)(pw + prow * 128 + ((c * 32 + 2 * fr) ^ ((prow & 7) << 4))) =
              (unsigned short)(pu.u >> 16);
        }
      short8 pf0 = *(const short8*)(pw + fr * 128 + ((fq * 16) ^ sw));
      short8 pf1 = *(const short8*)(pw + fr * 128 + ((64 + fq * 16) ^ sw));
      __builtin_amdgcn_s_setprio(1);
      floatx4 tsum = {};
      tsum = __builtin_amdgcn_mfma_f32_16x16x32_bf16(pf0, onesf, tsum, 0, 0, 0);
      tsum = __builtin_amdgcn_mfma_f32_16x16x32_bf16(pf1, onesf, tsum, 0, 0, 0);
#pragma unroll
      for (int d = 0; d < 4; ++d) {
        int rb = (d * 16 + fr) * 128;
        short8 vf0 = *(const short8*)(sVc + rb + ((fq * 16) ^ sw));
        short8 vf1 = *(const short8*)(sVc + rb + ((64 + fq * 16) ^ sw));
        oacc[d] = __builtin_amdgcn_mfma_f32_16x16x32_bf16(pf0, vf0, oacc[d], 0, 0, 0);
        oacc[d] = __builtin_amdgcn_mfma_f32_16x16x32_bf16(pf1, vf1, oacc[d], 0, 0, 0);
      }
      __builtin_amdgcn_s_setprio(0);
#pragma unroll
      for (int r = 0; r < 4; ++r) lrun[r] += tsum[r];
    }
    __builtin_amdgcn_sched_barrier(0);
    __builtin_amdgcn_s_barrier();
    if (t0 + 128 < tEnd) stage(cur, t0 + 128);
    cur ^= 1;
  }
  const int b = bh >> 4, h = bh & 15;
#pragma unroll
  for (int r = 0; r < 4; ++r) {
    float il = 1.0f / lrun[r];
#pragma unroll
    for (int d = 0; d < 4; ++d) {
      size_t o = ((size_t)b * 2048 + rowq + r) * 1024 + h * 64 + d * 16 + fr;
      out[o] = bfbits(oacc[d][r] * il);
    }
  }
}

extern "C" void kernel_launch(void* const* d_in, const int* in_sizes, int n_in,
                              void* d_out, int out_size, void* d_ws, size_t ws_size,
                              hipStream_t stream) {
  (void)in_sizes; (void)n_in; (void)out_size; (void)ws_size;
  const float* x  = (const float*)d_in[0];
  const float* Wq = (const float*)d_in[1];
  const float* bq = (const float*)d_in[2];
  const float* Wk = (const float*)d_in[3];
  const float* bk = (const float*)d_in[4];
  const float* Wv = (const float*)d_in[5];
  const float* bv = (const float*)d_in[6];
  const float* Wo = (const float*)d_in[7];
  const float* bo = (const float*)d_in[8];
  const float* lsc = (const float*)d_in[9];
  // d_in[10] = mask: fixed causal triu(k=1), implemented analytically.

  uint8_t* w = (uint8_t*)d_ws;
  const size_t MB = 1ull << 20;
  bf16* xb   = (bf16*)(w + 0);          // 8 MB
  bf16* wqb  = (bf16*)(w + 8 * MB);     // 2 MB each
  bf16* wkb  = (bf16*)(w + 10 * MB);
  bf16* wvb  = (bf16*)(w + 12 * MB);
  bf16* wob  = (bf16*)(w + 14 * MB);
  bf16* qbn  = (bf16*)(w + 16 * MB);    // 8 MB  [B,H,S,64]
  bf16* kbn  = (bf16*)(w + 24 * MB);    // 8 MB
  bf16* vtb  = (bf16*)(w + 32 * MB);    // 8 MB  [B,H,64,S]
  bf16* atb  = (bf16*)(w + 40 * MB);    // 8 MB  [B,S,DIM]
  float* tc  = (float*)(w + 48 * MB);   // 256 KB
  float* ts  = (float*)(w + 48 * MB + 256 * 1024);

  prep_kernel<<<8448, 256, 0, stream>>>(
      x, Wq, Wk, Wv, Wo, (unsigned short*)xb,
      (unsigned short*)wqb, (unsigned short*)wkb, (unsigned short*)wvb,
      (unsigned short*)wob, tc, ts);

  qkv_kernel<<<dim3(64, 48), 256, 0, stream>>>(
      xb, wqb, wkb, wvb, bq, bk, bv, tc, ts,
      (unsigned short*)qbn, (unsigned short*)kbn, (unsigned short*)vtb);

  attn_kernel<<<1024, 256, 0, stream>>>(qbn, kbn, vtb, lsc,
                                        (unsigned short*)atb);

  gemm_bt_kernel<<<dim3(64, 16), 256, 0, stream>>>(atb, wob, bo, (float*)d_out);
}